// Round 1
// baseline (197.729 us; speedup 1.0000x reference)
//
#include <hip/hip_runtime.h>
#include <math.h>

#define EPS_D 1e-6

__global__ void zero_accum(double* ws) {
    if (threadIdx.x < 2) ws[threadIdx.x] = 0.0;
}

__global__ __launch_bounds__(256) void theta_loss_main(
    const float* __restrict__ theta,
    const float* __restrict__ affine,
    double* __restrict__ ws, int n)
{
    int i = blockIdx.x * blockDim.x + threadIdx.x;
    double ortho = 0.0;
    double mse   = 0.0;
    if (i < n) {
        const float4* t4 = (const float4*)(theta) + 3 * (size_t)i;
        const float4* a4 = (const float4*)(affine) + 3 * (size_t)i;
        float4 t0 = t4[0], t1 = t4[1], t2 = t4[2];
        float4 a0 = a4[0], a1 = a4[1], a2 = a4[2];

        // ---- MSE over all 12 elements (fp32 inner, fp64 accumulate) ----
        float d, msef = 0.f;
        d = t0.x - a0.x; msef += d * d;
        d = t0.y - a0.y; msef += d * d;
        d = t0.z - a0.z; msef += d * d;
        d = t0.w - a0.w; msef += d * d;
        d = t1.x - a1.x; msef += d * d;
        d = t1.y - a1.y; msef += d * d;
        d = t1.z - a1.z; msef += d * d;
        d = t1.w - a1.w; msef += d * d;
        d = t2.x - a2.x; msef += d * d;
        d = t2.y - a2.y; msef += d * d;
        d = t2.z - a2.z; msef += d * d;
        d = t2.w - a2.w; msef += d * d;
        mse = (double)msef;

        // ---- W = theta[:, :, :3] rows, promote to fp64 ----
        double w00 = t0.x, w01 = t0.y, w02 = t0.z;
        double w10 = t1.x, w11 = t1.y, w12 = t1.z;
        double w20 = t2.x, w21 = t2.y, w22 = t2.z;

        // A = W^T W (symmetric PSD)
        double A00 = w00*w00 + w10*w10 + w20*w20;
        double A11 = w01*w01 + w11*w11 + w21*w21;
        double A22 = w02*w02 + w12*w12 + w22*w22;
        double A01 = w00*w01 + w10*w11 + w20*w21;
        double A02 = w00*w02 + w10*w12 + w20*w22;
        double A12 = w01*w02 + w11*w12 + w21*w22;

        // Closed-form symmetric 3x3 eigenvalues (trigonometric method), fp64
        double q  = (A00 + A11 + A22) * (1.0 / 3.0);
        double b00 = A00 - q, b11 = A11 - q, b22 = A22 - q;
        double p2 = b00*b00 + b11*b11 + b22*b22
                  + 2.0 * (A01*A01 + A02*A02 + A12*A12);
        double p  = sqrt(p2 * (1.0 / 6.0));
        double invp = (p > 0.0) ? 1.0 / p : 0.0;
        double c00 = b00 * invp, c11 = b11 * invp, c22 = b22 * invp;
        double c01 = A01 * invp, c02 = A02 * invp, c12 = A12 * invp;
        double detB = c00 * (c11 * c22 - c12 * c12)
                    - c01 * (c01 * c22 - c12 * c02)
                    + c02 * (c01 * c12 - c11 * c02);
        double r = 0.5 * detB;
        r = fmin(1.0, fmax(-1.0, r));
        double phi = acos(r) * (1.0 / 3.0);
        double sphi, cphi;
        sincos(phi, &sphi, &cphi);
        double l1 = q + 2.0 * p * cphi;                                      // largest
        double l3 = q + 2.0 * p * (-0.5 * cphi - 0.8660254037844386 * sphi); // smallest
        double l2 = 3.0 * q - l1 - l3;

        // Refine the smallest eigenvalue via det(W)^2 / (l1*l2):
        // avoids catastrophic cancellation when sigma_min is tiny — those
        // samples dominate the loss through (sigma+eps)^-2 ~ 1e12.
        double detW = w00 * (w11 * w22 - w12 * w21)
                    - w01 * (w10 * w22 - w12 * w20)
                    + w02 * (w10 * w21 - w11 * w20);
        double l12 = l1 * l2;
        if (l2 > 1e-12 * l1 && l12 > 0.0) l3 = (detW * detW) / l12;

        l1 = fmax(l1, 0.0); l2 = fmax(l2, 0.0); l3 = fmax(l3, 0.0);

        // Round sigma to fp32 (mimics the fp32 reference pipeline), add eps
        double s1 = (double)(float)sqrt(l1) + EPS_D;
        double s2 = (double)(float)sqrt(l2) + EPS_D;
        double s3 = (double)(float)sqrt(l3) + EPS_D;
        double q1 = s1 * s1, q2 = s2 * s2, q3 = s3 * s3;
        ortho = q1 + 1.0 / q1 + q2 + 1.0 / q2 + q3 + 1.0 / q3 - 6.0;
    }

    // ---- block reduction: wave64 shuffle -> LDS -> atomicAdd ----
    for (int off = 32; off > 0; off >>= 1) {
        ortho += __shfl_down(ortho, off);
        mse   += __shfl_down(mse, off);
    }
    __shared__ double so[4], sm[4];
    int lane = threadIdx.x & 63;
    int wv   = threadIdx.x >> 6;
    if (lane == 0) { so[wv] = ortho; sm[wv] = mse; }
    __syncthreads();
    if (threadIdx.x == 0) {
        double O = so[0] + so[1] + so[2] + so[3];
        double M = sm[0] + sm[1] + sm[2] + sm[3];
        atomicAdd(&ws[0], O);
        atomicAdd(&ws[1], M);
    }
}

__global__ void finalize_out(const double* __restrict__ ws,
                             float* __restrict__ out, int n) {
    if (threadIdx.x == 0) {
        out[0] = (float)(ws[0] / (double)n);
        out[1] = (float)(ws[1] / (12.0 * (double)n));
    }
}

extern "C" void kernel_launch(void* const* d_in, const int* in_sizes, int n_in,
                              void* d_out, int out_size, void* d_ws, size_t ws_size,
                              hipStream_t stream) {
    const float* theta  = (const float*)d_in[0];
    const float* affine = (const float*)d_in[1];
    double* ws = (double*)d_ws;
    float* out = (float*)d_out;
    int n = in_sizes[0] / 12;   // BATCH samples of 3x4

    zero_accum<<<1, 64, 0, stream>>>(ws);
    int blocks = (n + 255) / 256;
    theta_loss_main<<<blocks, 256, 0, stream>>>(theta, affine, ws, n);
    finalize_out<<<1, 64, 0, stream>>>(ws, out, n);
}

// Round 2
// 117.957 us; speedup vs baseline: 1.6763x; 1.6763x over previous
//
#include <hip/hip_runtime.h>
#include <math.h>

#define EPS_D 1e-6
#define SUB 256          // samples per sub-tile (== blockDim)
#define SPB (2 * SUB)    // samples per block

// Closed-form ortho term for one sample, no transcendentals beyond sqrt.
// Dominant-sample numerics intentionally identical to the R1-passing kernel:
// lambda_min via det^2/(lambda1*lambda2)-style fixed point (fp64), then
// fp64 sqrt -> fp32 round -> +eps -> 1/s^2.
__device__ __forceinline__ void sample_ortho(const float4 t0, const float4 t1,
                                             const float4 t2, double& ortho)
{
    double w00 = t0.x, w01 = t0.y, w02 = t0.z;
    double w10 = t1.x, w11 = t1.y, w12 = t1.z;
    double w20 = t2.x, w21 = t2.y, w22 = t2.z;

    // A = W^T W
    double A00 = w00*w00 + w10*w10 + w20*w20;
    double A11 = w01*w01 + w11*w11 + w21*w21;
    double A22 = w02*w02 + w12*w12 + w22*w22;
    double A01 = w00*w01 + w10*w11 + w20*w21;
    double A02 = w00*w02 + w10*w12 + w20*w22;
    double A12 = w01*w02 + w11*w12 + w21*w22;

    double I1 = A00 + A11 + A22;
    double I2 = (A00*A11 - A01*A01) + (A00*A22 - A02*A02) + (A11*A22 - A12*A12);
    double detW = w00*(w11*w22 - w12*w21)
                - w01*(w10*w22 - w12*w20)
                + w02*(w10*w21 - w11*w20);
    double I3 = detW * detW;   // = det(A) >= 0

    // Smallest eigenvalue: monotone fixed point lam <- I3 / q(lam),
    // q(lam) = lam^2 - I1*lam + I2 (= lam1*lam2 at lam=lam3).
    // Converges from below, never overshoots; for lam3 << lam2 converges
    // immediately (the dominant-loss samples).
    double lam = (I2 > 0.0) ? I3 / I2 : 0.0;
    #pragma unroll
    for (int it = 0; it < 6; ++it) {
        double q = (lam - I1) * lam + I2;
        lam = (q > 0.0) ? I3 / q : lam;
    }
    if (lam < 0.0) lam = 0.0;

    // Remaining two eigenvalues from the deflated quadratic.
    double S = I1 - lam;
    double P = (lam - I1) * lam + I2;    // ~ lam1*lam2
    double disc = S * S - 4.0 * P;
    disc = (disc > 0.0) ? sqrt(disc) : 0.0;
    double l1 = 0.5 * (S + disc); if (l1 < 0.0) l1 = 0.0;
    double l2 = 0.5 * (S - disc); if (l2 < 0.0) l2 = 0.0;

    double s1 = (double)(float)sqrt(l1) + EPS_D;
    double s2 = (double)(float)sqrt(l2) + EPS_D;
    double s3 = (double)(float)sqrt(lam) + EPS_D;
    double q1 = s1 * s1, q2 = s2 * s2, q3 = s3 * s3;
    double inv = 1.0 / (q1 * q2 * q3);
    ortho += (q1 + q2 + q3) + inv * (q2 * q3 + q1 * q3 + q1 * q2) - 6.0;
}

__global__ __launch_bounds__(256) void theta_loss_main(
    const float4* __restrict__ theta4,
    const float4* __restrict__ affine4,
    double* __restrict__ partial, int n)
{
    // 24 KB LDS: two 256-sample theta sub-tiles (affine never staged --
    // MSE is order-independent, accumulated during the coalesced pass).
    __shared__ float4 ldsA[3 * SUB];
    __shared__ float4 ldsB[3 * SUB];

    const int t = threadIdx.x;
    const int blockSample = blockIdx.x * SPB;
    const int n4 = n * 3;
    double mse = 0.0, ortho = 0.0;

    // ---- stage sub-tile 0 (coalesced float4: lane-consecutive) ----
    {
        int base4 = blockSample * 3;
        #pragma unroll
        for (int k = 0; k < 3; ++k) {
            int j = base4 + t + k * SUB;
            float4 tv = make_float4(0.f, 0.f, 0.f, 0.f);
            float4 av = make_float4(0.f, 0.f, 0.f, 0.f);
            if (j < n4) { tv = theta4[j]; av = affine4[j]; }
            float dx = tv.x - av.x, dy = tv.y - av.y;
            float dz = tv.z - av.z, dw = tv.w - av.w;
            mse += (double)(dx * dx + dy * dy) + (double)(dz * dz + dw * dw);
            ldsA[t + k * SUB] = tv;
        }
    }
    __syncthreads();

    // ---- issue sub-tile-1 global loads early (overlap with compute 0) ----
    float4 tvB[3], avB[3];
    {
        int base4 = (blockSample + SUB) * 3;
        #pragma unroll
        for (int k = 0; k < 3; ++k) {
            int j = base4 + t + k * SUB;
            tvB[k] = make_float4(0.f, 0.f, 0.f, 0.f);
            avB[k] = make_float4(0.f, 0.f, 0.f, 0.f);
            if (j < n4) { tvB[k] = theta4[j]; avB[k] = affine4[j]; }
        }
    }

    // ---- compute sub-tile 0 (stride-12-dword LDS reads: conflict-free) ----
    if (blockSample + t < n) {
        float4 a0 = ldsA[3 * t], a1 = ldsA[3 * t + 1], a2 = ldsA[3 * t + 2];
        sample_ortho(a0, a1, a2, ortho);
    }

    // ---- finish staging sub-tile 1 ----
    #pragma unroll
    for (int k = 0; k < 3; ++k) {
        float dx = tvB[k].x - avB[k].x, dy = tvB[k].y - avB[k].y;
        float dz = tvB[k].z - avB[k].z, dw = tvB[k].w - avB[k].w;
        mse += (double)(dx * dx + dy * dy) + (double)(dz * dz + dw * dw);
        ldsB[t + k * SUB] = tvB[k];
    }
    __syncthreads();

    // ---- compute sub-tile 1 ----
    if (blockSample + SUB + t < n) {
        float4 b0 = ldsB[3 * t], b1 = ldsB[3 * t + 1], b2 = ldsB[3 * t + 2];
        sample_ortho(b0, b1, b2, ortho);
    }

    // ---- block reduction: wave64 shuffle -> LDS -> per-block partial ----
    #pragma unroll
    for (int off = 32; off > 0; off >>= 1) {
        ortho += __shfl_down(ortho, off);
        mse   += __shfl_down(mse, off);
    }
    __shared__ double so[4], sm[4];
    int lane = t & 63, wv = t >> 6;
    if (lane == 0) { so[wv] = ortho; sm[wv] = mse; }
    __syncthreads();
    if (t == 0) {
        partial[2 * blockIdx.x]     = so[0] + so[1] + so[2] + so[3];
        partial[2 * blockIdx.x + 1] = sm[0] + sm[1] + sm[2] + sm[3];
    }
}

__global__ __launch_bounds__(256) void finalize_out(
    const double* __restrict__ partial, float* __restrict__ out,
    int nblocks, int n)
{
    double O = 0.0, M = 0.0;
    for (int i = threadIdx.x; i < nblocks; i += 256) {
        O += partial[2 * i];
        M += partial[2 * i + 1];
    }
    #pragma unroll
    for (int off = 32; off > 0; off >>= 1) {
        O += __shfl_down(O, off);
        M += __shfl_down(M, off);
    }
    __shared__ double so[4], sm[4];
    int lane = threadIdx.x & 63, wv = threadIdx.x >> 6;
    if (lane == 0) { so[wv] = O; sm[wv] = M; }
    __syncthreads();
    if (threadIdx.x == 0) {
        double Ot = so[0] + so[1] + so[2] + so[3];
        double Mt = sm[0] + sm[1] + sm[2] + sm[3];
        out[0] = (float)(Ot / (double)n);
        out[1] = (float)(Mt / (12.0 * (double)n));
    }
}

extern "C" void kernel_launch(void* const* d_in, const int* in_sizes, int n_in,
                              void* d_out, int out_size, void* d_ws, size_t ws_size,
                              hipStream_t stream) {
    const float4* theta4  = (const float4*)d_in[0];
    const float4* affine4 = (const float4*)d_in[1];
    double* partial = (double*)d_ws;
    float* out = (float*)d_out;
    int n = in_sizes[0] / 12;           // samples of 3x4

    int blocks = (n + SPB - 1) / SPB;   // 2048 for n = 1M
    theta_loss_main<<<blocks, 256, 0, stream>>>(theta4, affine4, partial, n);
    finalize_out<<<1, 256, 0, stream>>>(partial, out, blocks, n);
}